// Round 15
// baseline (690.588 us; speedup 1.0000x reference)
//
#include <hip/hip_runtime.h>
#include <hip/hip_bf16.h>

#define M_TOT 8192
#define N_TOT 16384
#define K_TOT 4096
#define NT (K_TOT / 64)  // 64 K-tiles of BK=64

typedef int i32x4 __attribute__((ext_vector_type(4)));
typedef int i32x16 __attribute__((ext_vector_type(16)));
typedef __bf16 bf16x8 __attribute__((ext_vector_type(8)));
typedef float f32x4 __attribute__((ext_vector_type(4)));

#define GLOAD_LDS16(g, l)                                                     \
  __builtin_amdgcn_global_load_lds(                                           \
      (__attribute__((address_space(1))) const void*)(g),                     \
      (__attribute__((address_space(3))) void*)(l), 16, 0, 0)

__device__ __forceinline__ ushort f2bf_rne(float f) {
  unsigned u = __float_as_uint(f);
  u += 0x7FFFu + ((u >> 16) & 1u);
  return (ushort)(u >> 16);
}
__device__ __forceinline__ ushort sgn_bf16(float w) {
  return w > 0.f ? (ushort)0x3F80u : (w < 0.f ? (ushort)0xBF80u : (ushort)0u);
}

// ============ Fragment-order (tiled) operand layouts (R10-verified) =========
// A_tiled: 1KB chunk (r32, kt, ks) at (r32*128 + kt*2 + ks)*1024; lane l
//   holds A[r32*32 + (l&31)][kt*64 + ks*32 + (l>>5)*16 .. +16).  (33.5 MB)
// B_tiled: same with n32: (n32*128 + kt*2 + ks)*1024.  (67 MB)

// ---------------- pass 1a: per-row amax + quantize x -> A_tiled --------------
__global__ void quant_x_kernel(const float* __restrict__ x,
                               char* __restrict__ At, float* __restrict__ s) {
  int row = blockIdx.x;
  int tid = threadIdx.x;
  const float4* xr = (const float4*)(x + (size_t)row * K_TOT + tid * 16);
  float4 v[4];
  float amax = 0.f;
#pragma unroll
  for (int j = 0; j < 4; ++j) {
    v[j] = xr[j];
    amax = fmaxf(amax, fmaxf(fmaxf(fabsf(v[j].x), fabsf(v[j].y)),
                             fmaxf(fabsf(v[j].z), fabsf(v[j].w))));
  }
#pragma unroll
  for (int o = 32; o > 0; o >>= 1) amax = fmaxf(amax, __shfl_xor(amax, o));
  __shared__ float wmax[4];
  if ((tid & 63) == 0) wmax[tid >> 6] = amax;
  __syncthreads();
  amax = fmaxf(fmaxf(wmax[0], wmax[1]), fmaxf(wmax[2], wmax[3]));
  float inv = amax > 0.f ? 127.0f / amax : 0.f;
  if (tid == 0) s[row] = amax * (1.0f / 127.0f);
  int q[16];
#pragma unroll
  for (int j = 0; j < 4; ++j) {
    q[j * 4 + 0] = max(-127, min(127, __float2int_rn(v[j].x * inv)));
    q[j * 4 + 1] = max(-127, min(127, __float2int_rn(v[j].y * inv)));
    q[j * 4 + 2] = max(-127, min(127, __float2int_rn(v[j].z * inv)));
    q[j * 4 + 3] = max(-127, min(127, __float2int_rn(v[j].w * inv)));
  }
  int4 o4;
  int* op = (int*)&o4;
#pragma unroll
  for (int j = 0; j < 4; ++j)
    op[j] = (q[j * 4] & 255) | ((q[j * 4 + 1] & 255) << 8) |
            ((q[j * 4 + 2] & 255) << 16) | ((q[j * 4 + 3] & 255) << 24);
  int r32 = row >> 5, l31 = row & 31;
  int kt = tid >> 2, ks = (tid >> 1) & 1, hi = tid & 1;
  size_t dst = ((size_t)(r32 * 128 + kt * 2 + ks) << 10) + ((hi * 32 + l31) << 4);
  *(int4*)(At + dst) = o4;
}

// ---------------- pass 1b: W -> sign i8 in B_tiled ----------------
__global__ void quant_w_kernel(const float* __restrict__ w,
                               char* __restrict__ Bt) {
  int n32 = blockIdx.x;  // 512 blocks
  int t = threadIdx.x;
#pragma unroll 4
  for (int i = 0; i < 32; ++i) {
    int c = i * 256 + t;
    int kt = c >> 7, ks = (c >> 6) & 1, l = c & 63;
    int n = n32 * 32 + (l & 31);
    int k = kt * 64 + ks * 32 + (l >> 5) * 16;
    const float4* src = (const float4*)(w + (size_t)n * K_TOT + k);
    int4 o4;
    int* op = (int*)&o4;
#pragma unroll
    for (int j = 0; j < 4; ++j) {
      float4 v = src[j];
      int q0 = v.x > 0.f ? 1 : (v.x < 0.f ? -1 : 0);
      int q1 = v.y > 0.f ? 1 : (v.y < 0.f ? -1 : 0);
      int q2 = v.z > 0.f ? 1 : (v.z < 0.f ? -1 : 0);
      int q3 = v.w > 0.f ? 1 : (v.w < 0.f ? -1 : 0);
      op[j] = (q0 & 255) | ((q1 & 255) << 8) | ((q2 & 255) << 16) |
              ((q3 & 255) << 24);
    }
    *(int4*)(Bt + ((size_t)n32 << 17) + ((size_t)c << 4)) = o4;
  }
}

// ---------------- pass 2: i8 GEMM, 256x256 tile, 4 FAT waves (128x128) ------
// C[m][n] = s[m]*(sum_k A8[m][k]*W8[n][k]) + bias[n]  (i32 accum, exact)
// R14 structure (passing, 565us GEMM) with the LDS-amplification lever:
// 256 threads = 4 waves (2M x 2N), wave-tile 128x128 = 4mi x 4ni of 32x32
// (acc 256 AGPR -> 1 wave/SIMD, launch_bounds(256,1), ~346 unified regs).
// Per wave per tile: 16 ds_read_b128 for 16384 outputs (was 12 for 8192) ->
// LDS reads 64KB/CU-tile (was 96KB); barrier convoy population halved.
// LDS: 4 bufs x (A 16KB | B 16KB) = 128KB, 1 block/CU.
// Schedule per tile t (buf t&3, stage 2 ahead, 8 gload_lds/thread/stage):
//   STAGE(t+2); vmcnt(8) [t+1 landed, t+2 in flight]; COMPUTE(t);
//   sched_barrier(0); s_barrier; sched_barrier(0).  (R14-proven fencing:
//   raw s_barrier is not a compiler fence; 4-buf gives a 2-barrier WAR window)
__global__ __launch_bounds__(256, 1) void gemm_i8_fat(
    const char* __restrict__ At, const char* __restrict__ Bt,
    const float* __restrict__ s, const float* __restrict__ bias,
    float* __restrict__ C) {
  __shared__ char lds[4][32768];  // [buf][A 16KB | B 16KB]

  // XCD swizzle: 2048 blocks (32 bm x 64 bn); per XCD one bn stripe
  // (8 bn x all 32 bm) = 256 contiguous wg.
  int bid = blockIdx.x;
  int wg = (bid & 7) * 256 + (bid >> 3);
  int bnS = wg >> 8;             // 0..7
  int rem = wg & 255;
  int bm = rem >> 3;             // 0..31
  int bn = bnS * 8 + (rem & 7);  // 0..63
  int rowBase = bm * 256;
  int colBase = bn * 256;

  int t = threadIdx.x;
  int lane = t & 63;
  int wave = t >> 6;   // 0..3
  int wr = wave >> 1;  // 0..1 -> M half (128)
  int wc = wave & 1;   // 0..1 -> N half (128)
  int l31 = lane & 31;
  int hi = lane >> 5;

  // staging: 2048 slots of 16B per buf; thread t covers ss = t + 256q,
  // q=0..7. q<4 -> A chunk g=ss>>6 (r32l=g>>1, ks=g&1); q>=4 -> B chunk g-16.
  const char* gp[8];
#pragma unroll
  for (int q = 0; q < 8; ++q) {
    int ss = t + 256 * q;
    int g = (ss >> 6) & 15;
    int r32l = g >> 1, ks = g & 1;
    int j = ss & 63;
    const char* base =
        (q < 4) ? At + ((size_t)((bm * 8 + r32l) * 128 + ks) << 10)
                : Bt + ((size_t)((bn * 8 + r32l) * 128 + ks) << 10);
    gp[q] = base + (j << 4);
  }

  i32x16 acc[4][4] = {};

#define STAGE(kt_, buf_)                                                      \
  {                                                                           \
    size_t _o = (size_t)(kt_) << 11;                                          \
    GLOAD_LDS16(gp[0] + _o, &lds[buf_][t * 16]);                              \
    GLOAD_LDS16(gp[1] + _o, &lds[buf_][4096 + t * 16]);                       \
    GLOAD_LDS16(gp[2] + _o, &lds[buf_][8192 + t * 16]);                       \
    GLOAD_LDS16(gp[3] + _o, &lds[buf_][12288 + t * 16]);                      \
    GLOAD_LDS16(gp[4] + _o, &lds[buf_][16384 + t * 16]);                      \
    GLOAD_LDS16(gp[5] + _o, &lds[buf_][20480 + t * 16]);                      \
    GLOAD_LDS16(gp[6] + _o, &lds[buf_][24576 + t * 16]);                      \
    GLOAD_LDS16(gp[7] + _o, &lds[buf_][28672 + t * 16]);                      \
  }
#define COMPUTE(buf_)                                                         \
  {                                                                           \
    const char* _la = &lds[buf_][0];                                          \
    const char* _lb = _la + 16384;                                            \
    _Pragma("unroll") for (int ks = 0; ks < 2; ++ks) {                        \
      i32x4 af[4], bf[4];                                                     \
      _Pragma("unroll") for (int mi = 0; mi < 4; ++mi)                        \
          af[mi] = *(const i32x4*)(_la + (((wr * 4 + mi) * 2 + ks) << 10) +   \
                                   (lane << 4));                              \
      _Pragma("unroll") for (int ni = 0; ni < 4; ++ni)                        \
          bf[ni] = *(const i32x4*)(_lb + (((wc * 4 + ni) * 2 + ks) << 10) +   \
                                   (lane << 4));                              \
      _Pragma("unroll") for (int mi = 0; mi < 4; ++mi)                        \
          _Pragma("unroll") for (int ni = 0; ni < 4; ++ni)                    \
              acc[mi][ni] = __builtin_amdgcn_mfma_i32_32x32x32_i8(            \
                  af[mi], bf[ni], acc[mi][ni], 0, 0, 0);                      \
    }                                                                         \
  }

  // prologue: tiles 0 and 1
  STAGE(0, 0);
  STAGE(1, 1);
  asm volatile("s_waitcnt vmcnt(8)" ::: "memory");  // tile0 landed
  __builtin_amdgcn_sched_barrier(0);
  __builtin_amdgcn_s_barrier();
  __builtin_amdgcn_sched_barrier(0);

  for (int tt = 0; tt < NT; ++tt) {
    int buf = tt & 3;
    if (tt + 2 < NT) {
      STAGE(tt + 2, (tt + 2) & 3);
      asm volatile("s_waitcnt vmcnt(8)" ::: "memory");  // tile t+1 landed
    } else if (tt + 1 < NT) {
      asm volatile("s_waitcnt vmcnt(0)" ::: "memory");  // drain last stage
    }
    COMPUTE(buf);
    __builtin_amdgcn_sched_barrier(0);  // nothing sinks past the barrier
    __builtin_amdgcn_s_barrier();
    __builtin_amdgcn_sched_barrier(0);  // nothing hoists above it
  }

#undef COMPUTE
#undef STAGE

  // epilogue: y = s[m] * acc + bias[n]
  // C/D 32x32: col = lane&31, row = (reg&3) + 8*(reg>>2) + 4*(lane>>5)
#pragma unroll
  for (int mi = 0; mi < 4; ++mi) {
#pragma unroll
    for (int ni = 0; ni < 4; ++ni) {
      int gc = colBase + wc * 128 + ni * 32 + l31;
      float bv = bias[gc];
#pragma unroll
      for (int rg = 0; rg < 16; ++rg) {
        int rowIn = (rg & 3) + 8 * (rg >> 2) + 4 * hi;
        int gr = rowBase + wr * 128 + mi * 32 + rowIn;
        C[(size_t)gr * N_TOT + gc] = (float)acc[mi][ni][rg] * s[gr] + bv;
      }
    }
  }
}

// ---------------- fallback (ws too small): fused bf16 conversion GEMM --------
__global__ void gemm_fused_kernel(const float* __restrict__ A,
                                  const float* __restrict__ W,
                                  const float* __restrict__ bias,
                                  float* __restrict__ C) {
  __shared__ ushort lsA[128 * 32];
  __shared__ ushort lsB[128 * 32];

  int nwg = gridDim.x;
  int bid = blockIdx.x;
  int wg = (bid & 7) * (nwg >> 3) + (bid >> 3);
  const int NBN = N_TOT / 128;
  int bm = wg / NBN;
  int bn = wg % NBN;
  int rowBase = bm * 128;
  int colBase = bn * 128;

  int t = threadIdx.x;
  int lane = t & 63;
  int wave = t >> 6;
  int wm = (wave >> 1) * 64;
  int wn = (wave & 1) * 64;

  f32x4 acc[4][4] = {};

  int srow = t >> 3;
  int scol = (t & 7) * 4;
  int fr = lane & 15;
  int koff = (lane >> 4) * 8;

  for (int k0 = 0; k0 < K_TOT; k0 += 32) {
    float4 va[4], vb[4];
#pragma unroll
    for (int r = 0; r < 4; ++r) {
      va[r] = *(const float4*)&A[(size_t)(rowBase + r * 32 + srow) * K_TOT + k0 + scol];
      vb[r] = *(const float4*)&W[(size_t)(colBase + r * 32 + srow) * K_TOT + k0 + scol];
    }
    __syncthreads();
#pragma unroll
    for (int r = 0; r < 4; ++r) {
      int e = r * 1024 + t * 4;
      ushort4 oa, ob;
      oa.x = f2bf_rne(va[r].x); oa.y = f2bf_rne(va[r].y);
      oa.z = f2bf_rne(va[r].z); oa.w = f2bf_rne(va[r].w);
      ob.x = sgn_bf16(vb[r].x); ob.y = sgn_bf16(vb[r].y);
      ob.z = sgn_bf16(vb[r].z); ob.w = sgn_bf16(vb[r].w);
      *(ushort4*)&lsA[e] = oa;
      *(ushort4*)&lsB[e] = ob;
    }
    __syncthreads();

    bf16x8 af[4], bfr[4];
#pragma unroll
    for (int i = 0; i < 4; ++i)
      af[i] = *(const bf16x8*)&lsA[(wm + i * 16 + fr) * 32 + koff];
#pragma unroll
    for (int j = 0; j < 4; ++j)
      bfr[j] = *(const bf16x8*)&lsB[(wn + j * 16 + fr) * 32 + koff];

#pragma unroll
    for (int i = 0; i < 4; ++i)
#pragma unroll
      for (int j = 0; j < 4; ++j)
        acc[i][j] = __builtin_amdgcn_mfma_f32_16x16x32_bf16(af[i], bfr[j],
                                                            acc[i][j], 0, 0, 0);
  }

  int orow0 = rowBase + wm + ((lane >> 4) << 2);
  int ocol0 = colBase + wn + (lane & 15);
#pragma unroll
  for (int i = 0; i < 4; ++i) {
#pragma unroll
    for (int j = 0; j < 4; ++j) {
      int col = ocol0 + j * 16;
      float bv = bias[col];
#pragma unroll
      for (int rg = 0; rg < 4; ++rg) {
        int row = orow0 + i * 16 + rg;
        C[(size_t)row * N_TOT + col] = acc[i][j][rg] + bv;
      }
    }
  }
}

extern "C" void kernel_launch(void* const* d_in, const int* in_sizes, int n_in,
                              void* d_out, int out_size, void* d_ws,
                              size_t ws_size, hipStream_t stream) {
  const float* x = (const float*)d_in[0];
  const float* W = (const float*)d_in[1];
  const float* b = (const float*)d_in[2];
  float* out = (float*)d_out;

  const size_t xq_bytes = (size_t)M_TOT * K_TOT;           // 33.5 MB
  const size_t wq_bytes = (size_t)N_TOT * K_TOT;           // 67.1 MB
  const size_t need = xq_bytes + wq_bytes + M_TOT * 4;     // ~101 MB

  if (ws_size >= need) {
    char* At = (char*)d_ws;
    char* Bt = At + xq_bytes;
    float* s = (float*)(Bt + wq_bytes);
    quant_x_kernel<<<M_TOT, 256, 0, stream>>>(x, At, s);
    quant_w_kernel<<<N_TOT / 32, 256, 0, stream>>>(W, Bt);
    const int nblocks = (M_TOT / 256) * (N_TOT / 256);  // 2048
    gemm_i8_fat<<<nblocks, 256, 0, stream>>>(At, Bt, s, b, out);
  } else {
    const int nblocks = (M_TOT / 128) * (N_TOT / 128);
    gemm_fused_kernel<<<nblocks, 256, 0, stream>>>(x, W, b, out);
  }
}

// Round 17
// 664.883 us; speedup vs baseline: 1.0387x; 1.0387x over previous
//
#include <hip/hip_runtime.h>
#include <hip/hip_bf16.h>

#define M_TOT 8192
#define N_TOT 16384
#define K_TOT 4096
#define NT (K_TOT / 64)  // 64 K-tiles of BK=64

typedef int i32x4 __attribute__((ext_vector_type(4)));
typedef int i32x16 __attribute__((ext_vector_type(16)));
typedef __bf16 bf16x8 __attribute__((ext_vector_type(8)));
typedef float f32x4 __attribute__((ext_vector_type(4)));

#define GLOAD_LDS16(g, l)                                                     \
  __builtin_amdgcn_global_load_lds(                                           \
      (__attribute__((address_space(1))) const void*)(g),                     \
      (__attribute__((address_space(3))) void*)(l), 16, 0, 0)

__device__ __forceinline__ ushort f2bf_rne(float f) {
  unsigned u = __float_as_uint(f);
  u += 0x7FFFu + ((u >> 16) & 1u);
  return (ushort)(u >> 16);
}
__device__ __forceinline__ ushort sgn_bf16(float w) {
  return w > 0.f ? (ushort)0x3F80u : (w < 0.f ? (ushort)0xBF80u : (ushort)0u);
}

// ============ Fragment-order (tiled) operand layouts (R10-verified) =========
// A_tiled: 1KB chunk (r32, kt, ks) at (r32*128 + kt*2 + ks)*1024; lane l
//   holds A[r32*32 + (l&31)][kt*64 + ks*32 + (l>>5)*16 .. +16).  (33.5 MB)
// B_tiled: same with n32: (n32*128 + kt*2 + ks)*1024.  (67 MB)

// ---------------- pass 1a: per-row amax + quantize x -> A_tiled --------------
__global__ void quant_x_kernel(const float* __restrict__ x,
                               char* __restrict__ At, float* __restrict__ s) {
  int row = blockIdx.x;
  int tid = threadIdx.x;
  const float4* xr = (const float4*)(x + (size_t)row * K_TOT + tid * 16);
  float4 v[4];
  float amax = 0.f;
#pragma unroll
  for (int j = 0; j < 4; ++j) {
    v[j] = xr[j];
    amax = fmaxf(amax, fmaxf(fmaxf(fabsf(v[j].x), fabsf(v[j].y)),
                             fmaxf(fabsf(v[j].z), fabsf(v[j].w))));
  }
#pragma unroll
  for (int o = 32; o > 0; o >>= 1) amax = fmaxf(amax, __shfl_xor(amax, o));
  __shared__ float wmax[4];
  if ((tid & 63) == 0) wmax[tid >> 6] = amax;
  __syncthreads();
  amax = fmaxf(fmaxf(wmax[0], wmax[1]), fmaxf(wmax[2], wmax[3]));
  float inv = amax > 0.f ? 127.0f / amax : 0.f;
  if (tid == 0) s[row] = amax * (1.0f / 127.0f);
  int q[16];
#pragma unroll
  for (int j = 0; j < 4; ++j) {
    q[j * 4 + 0] = max(-127, min(127, __float2int_rn(v[j].x * inv)));
    q[j * 4 + 1] = max(-127, min(127, __float2int_rn(v[j].y * inv)));
    q[j * 4 + 2] = max(-127, min(127, __float2int_rn(v[j].z * inv)));
    q[j * 4 + 3] = max(-127, min(127, __float2int_rn(v[j].w * inv)));
  }
  int4 o4;
  int* op = (int*)&o4;
#pragma unroll
  for (int j = 0; j < 4; ++j)
    op[j] = (q[j * 4] & 255) | ((q[j * 4 + 1] & 255) << 8) |
            ((q[j * 4 + 2] & 255) << 16) | ((q[j * 4 + 3] & 255) << 24);
  int r32 = row >> 5, l31 = row & 31;
  int kt = tid >> 2, ks = (tid >> 1) & 1, hi = tid & 1;
  size_t dst = ((size_t)(r32 * 128 + kt * 2 + ks) << 10) + ((hi * 32 + l31) << 4);
  *(int4*)(At + dst) = o4;
}

// ---------------- pass 1b: W -> sign i8 in B_tiled ----------------
__global__ void quant_w_kernel(const float* __restrict__ w,
                               char* __restrict__ Bt) {
  int n32 = blockIdx.x;  // 512 blocks
  int t = threadIdx.x;
#pragma unroll 4
  for (int i = 0; i < 32; ++i) {
    int c = i * 256 + t;
    int kt = c >> 7, ks = (c >> 6) & 1, l = c & 63;
    int n = n32 * 32 + (l & 31);
    int k = kt * 64 + ks * 32 + (l >> 5) * 16;
    const float4* src = (const float4*)(w + (size_t)n * K_TOT + k);
    int4 o4;
    int* op = (int*)&o4;
#pragma unroll
    for (int j = 0; j < 4; ++j) {
      float4 v = src[j];
      int q0 = v.x > 0.f ? 1 : (v.x < 0.f ? -1 : 0);
      int q1 = v.y > 0.f ? 1 : (v.y < 0.f ? -1 : 0);
      int q2 = v.z > 0.f ? 1 : (v.z < 0.f ? -1 : 0);
      int q3 = v.w > 0.f ? 1 : (v.w < 0.f ? -1 : 0);
      op[j] = (q0 & 255) | ((q1 & 255) << 8) | ((q2 & 255) << 16) |
              ((q3 & 255) << 24);
    }
    *(int4*)(Bt + ((size_t)n32 << 17) + ((size_t)c << 4)) = o4;
  }
}

// ------ pass 2: i8 GEMM, 256x256 tile, CROSS-BARRIER fragment pipeline ------
// C[m][n] = s[m]*(sum_k A8[m][k]*W8[n][k]) + bias[n]  (i32 accum, exact)
// R14 config (passing, 565us): 512 thr = 8 waves (2M x 4N), wave 128x64
// (4mi x 2ni, acc 128 AGPR), LDS 4 bufs x 32KB = 128KB, 1 block/CU,
// 2 waves/SIMD. Fragment reg sets X/Y pipelined so every MFMA cluster runs
// over INDEPENDENT in-flight ds_reads (m201 mechanism):
//   per tile t (buf=t&3):
//     1. STAGE(t+2 -> (t+2)&3)          [4 gload_lds/thread]
//     2. READ (t,ks1) -> Y              [6 ds_read, indep of step 3]
//     3. MFMA X (t,ks0)                 [16 MFMA; overlaps step 2]
//     4. vmcnt(4)  *** R16 BUG FIX: was vmcnt(8) = no-op with 4-load stages;
//        FIFO here = STAGE(t+1) 4 + STAGE(t+2) 4 = 8 outstanding, so
//        vmcnt(4) drains exactly the 4 oldest = STAGE(t+1). ***
//     5. fence; s_barrier; fence        [ALL waves' STAGE(t+1) landed]
//     6. READ (t+1,ks0) -> X            [6 ds_read, indep of step 7]
//     7. MFMA Y (t,ks1)                 [overlaps step 6]
// WAR safety (R16 audit stands): STAGE(t+2) rewrites buf(t-2), last read in
// tile t-2 and lgkm-consumed before the t-1 mid barrier; fences pin motion.
__global__ __launch_bounds__(512, 2) void gemm_i8_pipe(
    const char* __restrict__ At, const char* __restrict__ Bt,
    const float* __restrict__ s, const float* __restrict__ bias,
    float* __restrict__ C) {
  __shared__ char lds[4][32768];  // [buf][A 16KB | B 16KB]

  // XCD swizzle: 2048 blocks (32 bm x 64 bn); per XCD one bn stripe.
  int bid = blockIdx.x;
  int wg = (bid & 7) * 256 + (bid >> 3);
  int bnS = wg >> 8;
  int rem = wg & 255;
  int bm = rem >> 3;
  int bn = bnS * 8 + (rem & 7);
  int rowBase = bm * 256;
  int colBase = bn * 256;

  int t = threadIdx.x;
  int lane = t & 63;
  int wave = t >> 6;
  int wr = wave >> 2;  // 0..1 -> M half (128)
  int wc = wave & 3;   // 0..3 -> N quarter (64)
  int l31 = lane & 31;
  int hi = lane >> 5;

  const char* gAp[2];
  const char* gBp[2];
#pragma unroll
  for (int q = 0; q < 2; ++q) {
    int ss = t + 512 * q;
    int g = ss >> 6;
    int r32l = g >> 1, ks = g & 1;
    int j = ss & 63;
    gAp[q] = At + ((size_t)((bm * 8 + r32l) * 128 + ks) << 10) + (j << 4);
    gBp[q] = Bt + ((size_t)((bn * 8 + r32l) * 128 + ks) << 10) + (j << 4);
  }

  i32x16 acc[4][2] = {};
  i32x4 Xa[4], Xb[2], Ya[4], Yb[2];  // two static fragment sets

#define STAGE(kt_, buf_)                                                      \
  {                                                                           \
    size_t _o = (size_t)(kt_) << 11;                                          \
    GLOAD_LDS16(gAp[0] + _o, &lds[buf_][t * 16]);                             \
    GLOAD_LDS16(gAp[1] + _o, &lds[buf_][8192 + t * 16]);                      \
    GLOAD_LDS16(gBp[0] + _o, &lds[buf_][16384 + t * 16]);                     \
    GLOAD_LDS16(gBp[1] + _o, &lds[buf_][24576 + t * 16]);                     \
  }
#define READF(Adst, Bdst, buf_, ks_)                                          \
  {                                                                           \
    const char* _la = &lds[buf_][0];                                          \
    const char* _lb = _la + 16384;                                            \
    _Pragma("unroll") for (int mi = 0; mi < 4; ++mi)                          \
        Adst[mi] = *(const i32x4*)(_la + (((wr * 4 + mi) * 2 + (ks_)) << 10) + \
                                   (lane << 4));                              \
    _Pragma("unroll") for (int ni = 0; ni < 2; ++ni)                          \
        Bdst[ni] = *(const i32x4*)(_lb + (((wc * 2 + ni) * 2 + (ks_)) << 10) + \
                                   (lane << 4));                              \
  }
#define MFMACL(Asrc, Bsrc)                                                    \
  {                                                                           \
    __builtin_amdgcn_s_setprio(1);                                            \
    _Pragma("unroll") for (int mi = 0; mi < 4; ++mi) {                        \
      acc[mi][0] = __builtin_amdgcn_mfma_i32_32x32x32_i8(Asrc[mi], Bsrc[0],   \
                                                         acc[mi][0], 0, 0, 0); \
      acc[mi][1] = __builtin_amdgcn_mfma_i32_32x32x32_i8(Asrc[mi], Bsrc[1],   \
                                                         acc[mi][1], 0, 0, 0); \
    }                                                                         \
    __builtin_amdgcn_s_setprio(0);                                            \
  }

  // prologue: tiles 0 and 1 staged; vmcnt(4) drains STAGE(0) (8 outstanding);
  // barrier makes buf0 collectively landed; X = (0,ks0)
  STAGE(0, 0);
  STAGE(1, 1);
  asm volatile("s_waitcnt vmcnt(4)" ::: "memory");
  __builtin_amdgcn_sched_barrier(0);
  __builtin_amdgcn_s_barrier();
  __builtin_amdgcn_sched_barrier(0);
  READF(Xa, Xb, 0, 0);

  for (int tt = 0; tt < NT; ++tt) {
    int buf = tt & 3;
    if (tt + 2 < NT) STAGE(tt + 2, (tt + 2) & 3);
    READF(Ya, Yb, buf, 1);  // (t,ks1) — independent of MFMA below
    MFMACL(Xa, Xb);         // (t,ks0)
    if (tt + 2 < NT) {
      asm volatile("s_waitcnt vmcnt(4)" ::: "memory");  // drains STAGE(t+1)
    } else if (tt + 1 < NT) {
      asm volatile("s_waitcnt vmcnt(0)" ::: "memory");  // drain last stage
    }
    __builtin_amdgcn_sched_barrier(0);
    __builtin_amdgcn_s_barrier();  // collective: buf(t+1) fully written
    __builtin_amdgcn_sched_barrier(0);
    if (tt + 1 < NT) READF(Xa, Xb, (tt + 1) & 3, 0);  // (t+1,ks0) — indep
    MFMACL(Ya, Yb);                                   // (t,ks1)
  }

#undef MFMACL
#undef READF
#undef STAGE

  // epilogue: y = s[m] * acc + bias[n]
  // C/D 32x32: col = lane&31, row = (reg&3) + 8*(reg>>2) + 4*(lane>>5)
#pragma unroll
  for (int mi = 0; mi < 4; ++mi) {
#pragma unroll
    for (int ni = 0; ni < 2; ++ni) {
      int gc = colBase + wc * 64 + ni * 32 + l31;
      float bv = bias[gc];
#pragma unroll
      for (int rg = 0; rg < 16; ++rg) {
        int rowIn = (rg & 3) + 8 * (rg >> 2) + 4 * hi;
        int gr = rowBase + wr * 128 + mi * 32 + rowIn;
        C[(size_t)gr * N_TOT + gc] = (float)acc[mi][ni][rg] * s[gr] + bv;
      }
    }
  }
}

// ---------------- fallback (ws too small): fused bf16 conversion GEMM --------
__global__ void gemm_fused_kernel(const float* __restrict__ A,
                                  const float* __restrict__ W,
                                  const float* __restrict__ bias,
                                  float* __restrict__ C) {
  __shared__ ushort lsA[128 * 32];
  __shared__ ushort lsB[128 * 32];

  int nwg = gridDim.x;
  int bid = blockIdx.x;
  int wg = (bid & 7) * (nwg >> 3) + (bid >> 3);
  const int NBN = N_TOT / 128;
  int bm = wg / NBN;
  int bn = wg % NBN;
  int rowBase = bm * 128;
  int colBase = bn * 128;

  int t = threadIdx.x;
  int lane = t & 63;
  int wave = t >> 6;
  int wm = (wave >> 1) * 64;
  int wn = (wave & 1) * 64;

  f32x4 acc[4][4] = {};

  int srow = t >> 3;
  int scol = (t & 7) * 4;
  int fr = lane & 15;
  int koff = (lane >> 4) * 8;

  for (int k0 = 0; k0 < K_TOT; k0 += 32) {
    float4 va[4], vb[4];
#pragma unroll
    for (int r = 0; r < 4; ++r) {
      va[r] = *(const float4*)&A[(size_t)(rowBase + r * 32 + srow) * K_TOT + k0 + scol];
      vb[r] = *(const float4*)&W[(size_t)(colBase + r * 32 + srow) * K_TOT + k0 + scol];
    }
    __syncthreads();
#pragma unroll
    for (int r = 0; r < 4; ++r) {
      int e = r * 1024 + t * 4;
      ushort4 oa, ob;
      oa.x = f2bf_rne(va[r].x); oa.y = f2bf_rne(va[r].y);
      oa.z = f2bf_rne(va[r].z); oa.w = f2bf_rne(va[r].w);
      ob.x = sgn_bf16(vb[r].x); ob.y = sgn_bf16(vb[r].y);
      ob.z = sgn_bf16(vb[r].z); ob.w = sgn_bf16(vb[r].w);
      *(ushort4*)&lsA[e] = oa;
      *(ushort4*)&lsB[e] = ob;
    }
    __syncthreads();

    bf16x8 af[4], bfr[4];
#pragma unroll
    for (int i = 0; i < 4; ++i)
      af[i] = *(const bf16x8*)&lsA[(wm + i * 16 + fr) * 32 + koff];
#pragma unroll
    for (int j = 0; j < 4; ++j)
      bfr[j] = *(const bf16x8*)&lsB[(wn + j * 16 + fr) * 32 + koff];

#pragma unroll
    for (int i = 0; i < 4; ++i)
#pragma unroll
      for (int j = 0; j < 4; ++j)
        acc[i][j] = __builtin_amdgcn_mfma_f32_16x16x32_bf16(af[i], bfr[j],
                                                            acc[i][j], 0, 0, 0);
  }

  int orow0 = rowBase + wm + ((lane >> 4) << 2);
  int ocol0 = colBase + wn + (lane & 15);
#pragma unroll
  for (int i = 0; i < 4; ++i) {
#pragma unroll
    for (int j = 0; j < 4; ++j) {
      int col = ocol0 + j * 16;
      float bv = bias[col];
#pragma unroll
      for (int rg = 0; rg < 4; ++rg) {
        int row = orow0 + i * 16 + rg;
        C[(size_t)row * N_TOT + col] = acc[i][j][rg] + bv;
      }
    }
  }
}

extern "C" void kernel_launch(void* const* d_in, const int* in_sizes, int n_in,
                              void* d_out, int out_size, void* d_ws,
                              size_t ws_size, hipStream_t stream) {
  const float* x = (const float*)d_in[0];
  const float* W = (const float*)d_in[1];
  const float* b = (const float*)d_in[2];
  float* out = (float*)d_out;

  const size_t xq_bytes = (size_t)M_TOT * K_TOT;           // 33.5 MB
  const size_t wq_bytes = (size_t)N_TOT * K_TOT;           // 67.1 MB
  const size_t need = xq_bytes + wq_bytes + M_TOT * 4;     // ~101 MB

  if (ws_size >= need) {
    char* At = (char*)d_ws;
    char* Bt = At + xq_bytes;
    float* s = (float*)(Bt + wq_bytes);
    quant_x_kernel<<<M_TOT, 256, 0, stream>>>(x, At, s);
    quant_w_kernel<<<N_TOT / 32, 256, 0, stream>>>(W, Bt);
    const int nblocks = (M_TOT / 256) * (N_TOT / 256);  // 2048
    gemm_i8_pipe<<<nblocks, 512, 0, stream>>>(At, Bt, s, b, out);
  } else {
    const int nblocks = (M_TOT / 128) * (N_TOT / 128);
    gemm_fused_kernel<<<nblocks, 256, 0, stream>>>(x, W, b, out);
  }
}